// Round 16
// baseline (588.797 us; speedup 1.0000x reference)
//
#include <hip/hip_runtime.h>
#include <hip/hip_bf16.h>

#define N_ 1024
#define M_ 1152
#define L_ 32
#define NATSTRIDE (L_*M_)   // 36864
#define CONVK 129
#define OUTW 1024
#define NSTEP 31

typedef __attribute__((ext_vector_type(8))) short short8;
typedef __attribute__((ext_vector_type(4))) float f32x4;

__device__ __forceinline__ unsigned short f2bf(float f) {
    unsigned int u = __float_as_uint(f);
    u += 0x7FFFu + ((u >> 16) & 1u);   // round-to-nearest-even
    return (unsigned short)(u >> 16);
}
__device__ __forceinline__ float bf2f(unsigned short b) {
    return __uint_as_float(((unsigned int)b) << 16);
}

// w0t[m][k] (row-major bf16, for rpre_gemm) and w1blk k-chunk-blocked:
// w1blk[c*9216 + m*8 + e] = bf16(convW[m][8c+e][1])
__global__ __launch_bounds__(256) void build_wsplit(const float* __restrict__ convW,
                                                    unsigned short* __restrict__ w0t,
                                                    unsigned short* __restrict__ w1blk) {
    int idx = blockIdx.x * blockDim.x + threadIdx.x;
    if (idx >= M_ * M_) return;
    int m = idx / M_;
    int k = idx - m * M_;
    const float* s = convW + (size_t)m * (2 * M_) + 2 * k;
    w0t[idx] = f2bf(s[0]);
    int c = k >> 3, e = k & 7;
    w1blk[(size_t)c * 9216 + (size_t)m * 8 + e] = f2bf(s[1]);
}

// h0 (k-chunk-blocked): hblk[c*8192 + n*8 + e] = bf16(NATree[n][L-1][8c+e])
__global__ __launch_bounds__(256) void build_h0(const float* __restrict__ nat,
                                                unsigned short* __restrict__ hblk) {
    int idx = blockIdx.x * blockDim.x + threadIdx.x;   // one thread per 8 elems
    if (idx >= N_ * M_ / 8) return;
    int n = idx / (M_ / 8);
    int c = idx - n * (M_ / 8);
    const float* s = nat + (size_t)n * NATSTRIDE + (size_t)(L_ - 1) * M_ + c * 8;
    f32x4 v0 = *(const f32x4*)(s);
    f32x4 v1 = *(const f32x4*)(s + 4);
    short8 tt;
    #pragma unroll
    for (int e = 0; e < 4; ++e) {
        tt[e]     = (short)f2bf(v0[e]);
        tt[4 + e] = (short)f2bf(v1[e]);
    }
    *(short8*)(hblk + (size_t)c * 8192 + (size_t)n * 8) = tt;
}

// rbf[t][n][m] = bf16(NATree[n][30-t][m])  (row-major)
__global__ __launch_bounds__(256) void build_rbf(const float* __restrict__ nat,
                                                 unsigned short* __restrict__ rbf) {
    int idx = blockIdx.x * blockDim.x + threadIdx.x;   // one thread per 8 elems
    if (idx >= NSTEP * N_ * M_ / 8) return;
    int o = idx * 8;
    int t = o / (N_ * M_);
    int rem = o - t * (N_ * M_);
    int n = rem / M_;
    int m = rem - n * M_;
    int l = (NSTEP - 1) - t;
    const float* s = nat + (size_t)n * NATSTRIDE + (size_t)l * M_ + m;
    f32x4 v0 = *(const f32x4*)(s);
    f32x4 v1 = *(const f32x4*)(s + 4);
    short8 tt;
    #pragma unroll
    for (int e = 0; e < 4; ++e) {
        tt[e]     = (short)f2bf(v0[e]);
        tt[4 + e] = (short)f2bf(v1[e]);
    }
    *(short8*)(rbf + o) = tt;
}

// ---------------- Phase 1: Rpre = bf16( r_t @ W0^T + b ) for all t (unchanged) ----------------
#define P_BM 128
#define P_BN 128
#define P_BK 64
#define P_NT (M_ / P_BK)    // 18
#define P_LDP 72

__global__ __launch_bounds__(256) void rpre_gemm(
    const unsigned short* __restrict__ rbf,
    const unsigned short* __restrict__ w0t,
    const float* __restrict__ convb,
    unsigned short* __restrict__ rpre)
{
    __shared__ __align__(16) unsigned short As[2][P_BM * P_LDP];
    __shared__ __align__(16) unsigned short Bs[2][P_BN * P_LDP];

    int tid = threadIdx.x;
    int lane = tid & 63;
    int w = tid >> 6;
    int wr = w >> 1, wc = w & 1;
    int raw = blockIdx.y * 9 + blockIdx.x;
    int logical = (raw & 7) * 279 + (raw >> 3);   // 2232 = 8*279 bijective chunked swizzle
    int bx = logical % 9, by = logical / 9;
    int n0 = by * P_BM;
    int m0 = bx * P_BN;

    int lr = lane & 15;
    int lk = (lane >> 4) * 8;
    int srow = tid >> 3;
    int skcol = (tid & 7) * 8;

    f32x4 acc[4][4] = {};

    auto loadTile = [&](int it, short8 a[4], short8 b[4]) {
        int kb = it * P_BK;
        #pragma unroll
        for (int i = 0; i < 4; ++i) {
            int row = srow + i * 32;
            a[i] = *(const short8*)(rbf + (size_t)(n0 + row) * M_ + kb + skcol);
            b[i] = *(const short8*)(w0t + (size_t)(m0 + row) * M_ + kb + skcol);
        }
    };
    auto writeTile = [&](int buf, short8 a[4], short8 b[4]) {
        #pragma unroll
        for (int i = 0; i < 4; ++i) {
            *(short8*)&As[buf][(srow + i * 32) * P_LDP + skcol] = a[i];
            *(short8*)&Bs[buf][(srow + i * 32) * P_LDP + skcol] = b[i];
        }
    };

    {
        short8 a0[4], b0[4];
        loadTile(0, a0, b0);
        writeTile(0, a0, b0);
    }
    __syncthreads();

    int cur = 0;
    for (int it = 0; it < P_NT; ++it) {
        short8 a2[4], b2[4];
        if (it + 1 < P_NT) loadTile(it + 1, a2, b2);

        #pragma unroll
        for (int ks = 0; ks < P_BK; ks += 32) {
            short8 af[4], bf_[4];
            #pragma unroll
            for (int mi = 0; mi < 4; ++mi)
                af[mi] = *(const short8*)&As[cur][(wr * 64 + mi * 16 + lr) * P_LDP + ks + lk];
            #pragma unroll
            for (int ni = 0; ni < 4; ++ni)
                bf_[ni] = *(const short8*)&Bs[cur][(wc * 64 + ni * 16 + lr) * P_LDP + ks + lk];
            #pragma unroll
            for (int mi = 0; mi < 4; ++mi)
                #pragma unroll
                for (int ni = 0; ni < 4; ++ni)
                    acc[mi][ni] = __builtin_amdgcn_mfma_f32_16x16x32_bf16(
                        af[mi], bf_[ni], acc[mi][ni], 0, 0, 0);
        }
        if (it + 1 < P_NT) {
            writeTile(cur ^ 1, a2, b2);
            __syncthreads();
            cur ^= 1;
        }
    }

    #pragma unroll
    for (int mi = 0; mi < 4; ++mi) {
        #pragma unroll
        for (int ni = 0; ni < 4; ++ni) {
            int mloc = m0 + wc * 64 + ni * 16 + lr;
            float bias = convb[mloc];
            #pragma unroll
            for (int j = 0; j < 4; ++j) {
                int g = n0 + wr * 64 + mi * 16 + (lane >> 4) * 4 + j;
                rpre[(size_t)g * M_ + mloc] = f2bf(acc[mi][ni][j] + bias);
            }
        }
    }
}

// ---------------- Phase 3 (x31 launches): nolds_step, depth-9 queues ----------------
// 288 blocks = 8 rg (128 rows, XCD-affine via bid&7) x 36 cg (32 cols), 4 waves
// of 32x32. NO LDS, NO barriers; A (hblk) and B (w1blk) k-chunk-blocked so every
// fragment load is 256B-contiguous per quarter-wave from the XCD-local L2.
// Register queues 9 deep (36%9==0): ~225cy of cover ≈ L2 hit latency.
__global__ __launch_bounds__(256) void nolds_step(
    const unsigned short* __restrict__ hin,     // blocked h
    const unsigned short* __restrict__ w1blk,   // blocked W1
    const unsigned short* __restrict__ rpre_t,
    const unsigned short* __restrict__ rbf_t,
    const float* __restrict__ x,
    unsigned short* __restrict__ hout,          // blocked h
    float* __restrict__ resOut,
    int final_step)
{
    int tid = threadIdx.x;
    int lane = tid & 63;
    int w = tid >> 6;                 // wave -> rows [32w, 32w+32)
    int bid = blockIdx.x;
    int rg = bid & 7;
    int cg = bid >> 3;                // 0..35
    int n0 = rg * 128;
    int m0 = cg * 32;
    int lr = lane & 15;
    int lg = lane >> 4;

    // A: rows R0, R0+16; B: cols m0+lr, m0+16+lr — all chunk-blocked, coalesced
    int R0 = n0 + 32 * w + lr;
    const unsigned short* hb0 = hin + (size_t)R0 * 8;
    const unsigned short* hb1 = hb0 + 16 * 8;
    const unsigned short* wb0 = w1blk + (size_t)(m0 + lr) * 8;
    const unsigned short* wb1 = wb0 + 16 * 8;

    short8 aQ[9][2], bQ[9][2];
    auto loadQ = [&](int it) {
        int s = it % 9;
        size_t ca = (size_t)(it * 4 + lg) * 8192;
        size_t cb = (size_t)(it * 4 + lg) * 9216;
        aQ[s][0] = *(const short8*)(hb0 + ca);
        aQ[s][1] = *(const short8*)(hb1 + ca);
        bQ[s][0] = *(const short8*)(wb0 + cb);
        bQ[s][1] = *(const short8*)(wb1 + cb);
    };
    #pragma unroll
    for (int p = 0; p < 9; ++p) loadQ(p);

    // epilogue operand prefetch (latency hides under the K-loop)
    unsigned short preR[2][2][4], rbfR[2][2][4];
    #pragma unroll
    for (int mi = 0; mi < 2; ++mi)
        #pragma unroll
        for (int ni = 0; ni < 2; ++ni) {
            int mloc = m0 + ni * 16 + lr;
            #pragma unroll
            for (int j = 0; j < 4; ++j) {
                int nloc = n0 + 32 * w + 16 * mi + lg * 4 + j;
                preR[mi][ni][j] = rpre_t[(size_t)nloc * M_ + mloc];
                rbfR[mi][ni][j] = rbf_t[(size_t)nloc * M_ + mloc];
            }
        }

    // barrier-free K-loop: 36 iters, fully unrolled, 4 MFMA/iter
    f32x4 acc[2][2] = {};
    #pragma unroll
    for (int it = 0; it < 36; ++it) {
        int s = it % 9;   // compile-time (loop unrolled)
        #pragma unroll
        for (int mi = 0; mi < 2; ++mi)
            #pragma unroll
            for (int ni = 0; ni < 2; ++ni)
                acc[mi][ni] = __builtin_amdgcn_mfma_f32_16x16x32_bf16(
                    aQ[s][mi], bQ[s][ni], acc[mi][ni], 0, 0, 0);
        if (it + 9 < 36) loadQ(it + 9);
    }

    // epilogue (plain stores; dispatch boundary provides coherence)
    #pragma unroll
    for (int mi = 0; mi < 2; ++mi) {
        #pragma unroll
        for (int ni = 0; ni < 2; ++ni) {
            int mloc = m0 + ni * 16 + lr;
            int cB = mloc >> 3, eB = mloc & 7;
            #pragma unroll
            for (int j = 0; j < 4; ++j) {
                int nloc = n0 + 32 * w + 16 * mi + lg * 4 + j;
                float pre = acc[mi][ni][j] + bf2f(preR[mi][ni][j]);
                float hv = tanhf(pre) + bf2f(rbfR[mi][ni][j]);
                if (final_step) {
                    resOut[(size_t)nloc * M_ + mloc] = tanhf(tanhf(hv) + x[(size_t)nloc * M_ + mloc]);
                } else {
                    hout[(size_t)cB * 8192 + (size_t)nloc * 8 + eB] = f2bf(hv);
                }
            }
        }
    }
}

// out[n][j] = conv2b + sum_k res[n][j+k] * conv2W[k]
__global__ __launch_bounds__(256) void conv_out_kernel(
    const float* __restrict__ res, const float* __restrict__ w2,
    const float* __restrict__ b2, float* __restrict__ out)
{
    __shared__ float row[M_];
    __shared__ float wk[CONVK];
    int n = blockIdx.x;
    int tid = threadIdx.x;
    for (int i = tid; i < M_; i += 256) row[i] = res[(size_t)n * M_ + i];
    if (tid < CONVK) wk[tid] = w2[tid];
    __syncthreads();
    float b = b2[0];
    int j0 = tid * 4;
    float s0 = b, s1 = b, s2 = b, s3 = b;
    float r0 = row[j0], r1 = row[j0 + 1], r2 = row[j0 + 2], r3 = row[j0 + 3];
    for (int k = 0; k < CONVK; ++k) {
        float wv = wk[k];
        s0 += r0 * wv; s1 += r1 * wv; s2 += r2 * wv; s3 += r3 * wv;
        if (k < CONVK - 1) { r0 = r1; r1 = r2; r2 = r3; r3 = row[j0 + 4 + k]; }
    }
    float* o = out + (size_t)n * OUTW + j0;
    o[0] = s0; o[1] = s1; o[2] = s2; o[3] = s3;
}

extern "C" void kernel_launch(void* const* d_in, const int* in_sizes, int n_in,
                              void* d_out, int out_size, void* d_ws, size_t ws_size,
                              hipStream_t stream) {
    const float* NATree = (const float*)d_in[0];
    const float* x      = (const float*)d_in[1];
    const float* convW  = (const float*)d_in[2];
    const float* convb  = (const float*)d_in[3];
    const float* conv2W = (const float*)d_in[4];
    const float* conv2b = (const float*)d_in[5];
    float* out = (float*)d_out;

    char* ws = (char*)d_ws;
    size_t off = 0;
    auto alloc = [&](size_t bytes) {
        void* p = ws + off;
        off = (off + bytes + 255) & ~(size_t)255;
        return p;
    };
    unsigned short* w0t   = (unsigned short*)alloc((size_t)M_ * M_ * 2);
    unsigned short* w1blk = (unsigned short*)alloc((size_t)M_ * M_ * 2);
    unsigned short* hA    = (unsigned short*)alloc((size_t)N_ * M_ * 2);
    unsigned short* hB    = (unsigned short*)alloc((size_t)N_ * M_ * 2);
    unsigned short* rpre  = (unsigned short*)alloc((size_t)NSTEP * N_ * M_ * 2);
    unsigned short* rbf   = (unsigned short*)alloc((size_t)NSTEP * N_ * M_ * 2);
    float*          res   = (float*)alloc((size_t)N_ * M_ * 4);

    build_wsplit<<<(M_ * M_ + 255) / 256, 256, 0, stream>>>(convW, w0t, w1blk);
    build_h0<<<(N_ * M_ / 8 + 255) / 256, 256, 0, stream>>>(NATree, hA);
    build_rbf<<<(NSTEP * N_ * M_ / 8 + 255) / 256, 256, 0, stream>>>(NATree, rbf);

    // Phase 1: all 31 r_t @ W0^T + b in one GEMM (M = 31744)
    rpre_gemm<<<dim3(M_ / P_BN, (NSTEP * N_) / P_BM), 256, 0, stream>>>(rbf, w0t, convb, rpre);

    // Phase 3: sequential h-chain, no-LDS barrier-free step, depth-9 queues
    const unsigned short* hin = hA;
    unsigned short* hout = hB;
    for (int t = 0; t < NSTEP; ++t) {
        int fin = (t == NSTEP - 1) ? 1 : 0;
        nolds_step<<<288, 256, 0, stream>>>(
            hin, w1blk, rpre + (size_t)t * N_ * M_, rbf + (size_t)t * N_ * M_,
            x, hout, res, fin);
        unsigned short* tmp = hout;
        hout = (unsigned short*)hin;
        hin = tmp;
    }

    conv_out_kernel<<<1024, 256, 0, stream>>>(res, conv2W, conv2b, out);
}

// Round 17
// 574.764 us; speedup vs baseline: 1.0244x; 1.0244x over previous
//
#include <hip/hip_runtime.h>
#include <hip/hip_bf16.h>

#define N_ 1024
#define M_ 1152
#define L_ 32
#define NATSTRIDE (L_*M_)   // 36864
#define CONVK 129
#define OUTW 1024
#define NSTEP 31

typedef __attribute__((ext_vector_type(8))) short short8;
typedef __attribute__((ext_vector_type(4))) float f32x4;

__device__ __forceinline__ unsigned short f2bf(float f) {
    unsigned int u = __float_as_uint(f);
    u += 0x7FFFu + ((u >> 16) & 1u);   // round-to-nearest-even
    return (unsigned short)(u >> 16);
}
__device__ __forceinline__ float bf2f(unsigned short b) {
    return __uint_as_float(((unsigned int)b) << 16);
}

// async global->LDS, 16B per lane; lds dest = wave-uniform base + lane*16
__device__ __forceinline__ void gll16(const unsigned short* g, unsigned short* l) {
    __builtin_amdgcn_global_load_lds(
        (const __attribute__((address_space(1))) unsigned int*)g,
        (__attribute__((address_space(3))) unsigned int*)l,
        16, 0, 0);
}

// w0t[m][k] (row-major bf16, for rpre_gemm) and w1blk k-chunk-blocked:
// w1blk[c*9216 + m*8 + e] = bf16(convW[m][8c+e][1])
__global__ __launch_bounds__(256) void build_wsplit(const float* __restrict__ convW,
                                                    unsigned short* __restrict__ w0t,
                                                    unsigned short* __restrict__ w1blk) {
    int idx = blockIdx.x * blockDim.x + threadIdx.x;
    if (idx >= M_ * M_) return;
    int m = idx / M_;
    int k = idx - m * M_;
    const float* s = convW + (size_t)m * (2 * M_) + 2 * k;
    w0t[idx] = f2bf(s[0]);
    int c = k >> 3, e = k & 7;
    w1blk[(size_t)c * 9216 + (size_t)m * 8 + e] = f2bf(s[1]);
}

// h0 (k-chunk-blocked): hblk[c*8192 + n*8 + e] = bf16(NATree[n][L-1][8c+e])
__global__ __launch_bounds__(256) void build_h0(const float* __restrict__ nat,
                                                unsigned short* __restrict__ hblk) {
    int idx = blockIdx.x * blockDim.x + threadIdx.x;   // one thread per 8 elems
    if (idx >= N_ * M_ / 8) return;
    int n = idx / (M_ / 8);
    int c = idx - n * (M_ / 8);
    const float* s = nat + (size_t)n * NATSTRIDE + (size_t)(L_ - 1) * M_ + c * 8;
    f32x4 v0 = *(const f32x4*)(s);
    f32x4 v1 = *(const f32x4*)(s + 4);
    short8 tt;
    #pragma unroll
    for (int e = 0; e < 4; ++e) {
        tt[e]     = (short)f2bf(v0[e]);
        tt[4 + e] = (short)f2bf(v1[e]);
    }
    *(short8*)(hblk + (size_t)c * 8192 + (size_t)n * 8) = tt;
}

// rbf[t][n][m] = bf16(NATree[n][30-t][m])  (row-major)
__global__ __launch_bounds__(256) void build_rbf(const float* __restrict__ nat,
                                                 unsigned short* __restrict__ rbf) {
    int idx = blockIdx.x * blockDim.x + threadIdx.x;   // one thread per 8 elems
    if (idx >= NSTEP * N_ * M_ / 8) return;
    int o = idx * 8;
    int t = o / (N_ * M_);
    int rem = o - t * (N_ * M_);
    int n = rem / M_;
    int m = rem - n * M_;
    int l = (NSTEP - 1) - t;
    const float* s = nat + (size_t)n * NATSTRIDE + (size_t)l * M_ + m;
    f32x4 v0 = *(const f32x4*)(s);
    f32x4 v1 = *(const f32x4*)(s + 4);
    short8 tt;
    #pragma unroll
    for (int e = 0; e < 4; ++e) {
        tt[e]     = (short)f2bf(v0[e]);
        tt[4 + e] = (short)f2bf(v1[e]);
    }
    *(short8*)(rbf + o) = tt;
}

// ---------------- Phase 1: Rpre = bf16( r_t @ W0^T + b ), m97 structure ----------------
// 128x128 tile, BK=64, SINGLE 32KB linear LDS buffer, global_load_lds width-16
// staging (no VGPR round-trip), 2 barriers/K-tile; ~4 blocks/CU co-resident.
#define P_BM 128
#define P_BN 128
#define P_BK 64
#define P_NT (M_ / P_BK)    // 18

__global__ __launch_bounds__(256) void rpre_gemm(
    const unsigned short* __restrict__ rbf,
    const unsigned short* __restrict__ w0t,
    const float* __restrict__ convb,
    unsigned short* __restrict__ rpre)
{
    __shared__ __align__(16) unsigned short As[P_BM * P_BK];   // 16 KB, linear [row][64]
    __shared__ __align__(16) unsigned short Bs[P_BN * P_BK];   // 16 KB

    int tid = threadIdx.x;
    int lane = tid & 63;
    int w = tid >> 6;
    int wr = w >> 1, wc = w & 1;
    int raw = blockIdx.y * 9 + blockIdx.x;
    int logical = (raw & 7) * 279 + (raw >> 3);   // 2232 = 8*279 bijective chunked swizzle
    int bx = logical % 9, by = logical / 9;
    int n0 = by * P_BM;
    int m0 = bx * P_BN;

    int lr = lane & 15;
    int lk = (lane >> 4) * 8;
    int wbase = tid & ~63;            // wave-uniform chunk base (w*64)

    f32x4 acc[4][4] = {};

    for (int it = 0; it < P_NT; ++it) {
        int kb = it * P_BK;
        if (it) __syncthreads();      // prev compute done before overwrite
        #pragma unroll
        for (int i = 0; i < 4; ++i) {
            int c = i * 256 + tid;    // chunk: row = c>>3, kcol = (c&7)*8
            int row = c >> 3;
            int kc = (c & 7) * 8;
            int lb = (i * 256 + wbase) * 8;   // wave-uniform LDS elem base
            gll16(rbf + (size_t)(n0 + row) * M_ + kb + kc, &As[lb]);
            gll16(w0t + (size_t)(m0 + row) * M_ + kb + kc, &Bs[lb]);
        }
        __syncthreads();              // implicit vmcnt(0) drain -> tiles ready

        #pragma unroll
        for (int ks = 0; ks < P_BK; ks += 32) {
            short8 af[4], bf_[4];
            #pragma unroll
            for (int mi = 0; mi < 4; ++mi)
                af[mi] = *(const short8*)&As[(wr * 64 + mi * 16 + lr) * P_BK + ks + lk];
            #pragma unroll
            for (int ni = 0; ni < 4; ++ni)
                bf_[ni] = *(const short8*)&Bs[(wc * 64 + ni * 16 + lr) * P_BK + ks + lk];
            #pragma unroll
            for (int mi = 0; mi < 4; ++mi)
                #pragma unroll
                for (int ni = 0; ni < 4; ++ni)
                    acc[mi][ni] = __builtin_amdgcn_mfma_f32_16x16x32_bf16(
                        af[mi], bf_[ni], acc[mi][ni], 0, 0, 0);
        }
    }

    #pragma unroll
    for (int mi = 0; mi < 4; ++mi) {
        #pragma unroll
        for (int ni = 0; ni < 4; ++ni) {
            int mloc = m0 + wc * 64 + ni * 16 + lr;
            float bias = convb[mloc];
            #pragma unroll
            for (int j = 0; j < 4; ++j) {
                int g = n0 + wr * 64 + mi * 16 + (lane >> 4) * 4 + j;
                rpre[(size_t)g * M_ + mloc] = f2bf(acc[mi][ni][j] + bias);
            }
        }
    }
}

// ---------------- Phase 3 (x31 launches): nolds_step, depth-9 queues (R16) ----------------
__global__ __launch_bounds__(256) void nolds_step(
    const unsigned short* __restrict__ hin,     // blocked h
    const unsigned short* __restrict__ w1blk,   // blocked W1
    const unsigned short* __restrict__ rpre_t,
    const unsigned short* __restrict__ rbf_t,
    const float* __restrict__ x,
    unsigned short* __restrict__ hout,          // blocked h
    float* __restrict__ resOut,
    int final_step)
{
    int tid = threadIdx.x;
    int lane = tid & 63;
    int w = tid >> 6;                 // wave -> rows [32w, 32w+32)
    int bid = blockIdx.x;
    int rg = bid & 7;
    int cg = bid >> 3;                // 0..35
    int n0 = rg * 128;
    int m0 = cg * 32;
    int lr = lane & 15;
    int lg = lane >> 4;

    int R0 = n0 + 32 * w + lr;
    const unsigned short* hb0 = hin + (size_t)R0 * 8;
    const unsigned short* hb1 = hb0 + 16 * 8;
    const unsigned short* wb0 = w1blk + (size_t)(m0 + lr) * 8;
    const unsigned short* wb1 = wb0 + 16 * 8;

    short8 aQ[9][2], bQ[9][2];
    auto loadQ = [&](int it) {
        int s = it % 9;
        size_t ca = (size_t)(it * 4 + lg) * 8192;
        size_t cb = (size_t)(it * 4 + lg) * 9216;
        aQ[s][0] = *(const short8*)(hb0 + ca);
        aQ[s][1] = *(const short8*)(hb1 + ca);
        bQ[s][0] = *(const short8*)(wb0 + cb);
        bQ[s][1] = *(const short8*)(wb1 + cb);
    };
    #pragma unroll
    for (int p = 0; p < 9; ++p) loadQ(p);

    unsigned short preR[2][2][4], rbfR[2][2][4];
    #pragma unroll
    for (int mi = 0; mi < 2; ++mi)
        #pragma unroll
        for (int ni = 0; ni < 2; ++ni) {
            int mloc = m0 + ni * 16 + lr;
            #pragma unroll
            for (int j = 0; j < 4; ++j) {
                int nloc = n0 + 32 * w + 16 * mi + lg * 4 + j;
                preR[mi][ni][j] = rpre_t[(size_t)nloc * M_ + mloc];
                rbfR[mi][ni][j] = rbf_t[(size_t)nloc * M_ + mloc];
            }
        }

    f32x4 acc[2][2] = {};
    #pragma unroll
    for (int it = 0; it < 36; ++it) {
        int s = it % 9;   // compile-time (loop unrolled)
        #pragma unroll
        for (int mi = 0; mi < 2; ++mi)
            #pragma unroll
            for (int ni = 0; ni < 2; ++ni)
                acc[mi][ni] = __builtin_amdgcn_mfma_f32_16x16x32_bf16(
                    aQ[s][mi], bQ[s][ni], acc[mi][ni], 0, 0, 0);
        if (it + 9 < 36) loadQ(it + 9);
    }

    #pragma unroll
    for (int mi = 0; mi < 2; ++mi) {
        #pragma unroll
        for (int ni = 0; ni < 2; ++ni) {
            int mloc = m0 + ni * 16 + lr;
            int cB = mloc >> 3, eB = mloc & 7;
            #pragma unroll
            for (int j = 0; j < 4; ++j) {
                int nloc = n0 + 32 * w + 16 * mi + lg * 4 + j;
                float pre = acc[mi][ni][j] + bf2f(preR[mi][ni][j]);
                float hv = tanhf(pre) + bf2f(rbfR[mi][ni][j]);
                if (final_step) {
                    resOut[(size_t)nloc * M_ + mloc] = tanhf(tanhf(hv) + x[(size_t)nloc * M_ + mloc]);
                } else {
                    hout[(size_t)cB * 8192 + (size_t)nloc * 8 + eB] = f2bf(hv);
                }
            }
        }
    }
}

// out[n][j] = conv2b + sum_k res[n][j+k] * conv2W[k]
__global__ __launch_bounds__(256) void conv_out_kernel(
    const float* __restrict__ res, const float* __restrict__ w2,
    const float* __restrict__ b2, float* __restrict__ out)
{
    __shared__ float row[M_];
    __shared__ float wk[CONVK];
    int n = blockIdx.x;
    int tid = threadIdx.x;
    for (int i = tid; i < M_; i += 256) row[i] = res[(size_t)n * M_ + i];
    if (tid < CONVK) wk[tid] = w2[tid];
    __syncthreads();
    float b = b2[0];
    int j0 = tid * 4;
    float s0 = b, s1 = b, s2 = b, s3 = b;
    float r0 = row[j0], r1 = row[j0 + 1], r2 = row[j0 + 2], r3 = row[j0 + 3];
    for (int k = 0; k < CONVK; ++k) {
        float wv = wk[k];
        s0 += r0 * wv; s1 += r1 * wv; s2 += r2 * wv; s3 += r3 * wv;
        if (k < CONVK - 1) { r0 = r1; r1 = r2; r2 = r3; r3 = row[j0 + 4 + k]; }
    }
    float* o = out + (size_t)n * OUTW + j0;
    o[0] = s0; o[1] = s1; o[2] = s2; o[3] = s3;
}

extern "C" void kernel_launch(void* const* d_in, const int* in_sizes, int n_in,
                              void* d_out, int out_size, void* d_ws, size_t ws_size,
                              hipStream_t stream) {
    const float* NATree = (const float*)d_in[0];
    const float* x      = (const float*)d_in[1];
    const float* convW  = (const float*)d_in[2];
    const float* convb  = (const float*)d_in[3];
    const float* conv2W = (const float*)d_in[4];
    const float* conv2b = (const float*)d_in[5];
    float* out = (float*)d_out;

    char* ws = (char*)d_ws;
    size_t off = 0;
    auto alloc = [&](size_t bytes) {
        void* p = ws + off;
        off = (off + bytes + 255) & ~(size_t)255;
        return p;
    };
    unsigned short* w0t   = (unsigned short*)alloc((size_t)M_ * M_ * 2);
    unsigned short* w1blk = (unsigned short*)alloc((size_t)M_ * M_ * 2);
    unsigned short* hA    = (unsigned short*)alloc((size_t)N_ * M_ * 2);
    unsigned short* hB    = (unsigned short*)alloc((size_t)N_ * M_ * 2);
    unsigned short* rpre  = (unsigned short*)alloc((size_t)NSTEP * N_ * M_ * 2);
    unsigned short* rbf   = (unsigned short*)alloc((size_t)NSTEP * N_ * M_ * 2);
    float*          res   = (float*)alloc((size_t)N_ * M_ * 4);

    build_wsplit<<<(M_ * M_ + 255) / 256, 256, 0, stream>>>(convW, w0t, w1blk);
    build_h0<<<(N_ * M_ / 8 + 255) / 256, 256, 0, stream>>>(NATree, hA);
    build_rbf<<<(NSTEP * N_ * M_ / 8 + 255) / 256, 256, 0, stream>>>(NATree, rbf);

    // Phase 1: all 31 r_t @ W0^T + b in one GEMM (M = 31744), gll-staged
    rpre_gemm<<<dim3(M_ / P_BN, (NSTEP * N_) / P_BM), 256, 0, stream>>>(rbf, w0t, convb, rpre);

    // Phase 3: sequential h-chain, no-LDS barrier-free step, depth-9 queues
    const unsigned short* hin = hA;
    unsigned short* hout = hB;
    for (int t = 0; t < NSTEP; ++t) {
        int fin = (t == NSTEP - 1) ? 1 : 0;
        nolds_step<<<288, 256, 0, stream>>>(
            hin, w1blk, rpre + (size_t)t * N_ * M_, rbf + (size_t)t * N_ * M_,
            x, hout, res, fin);
        unsigned short* tmp = hout;
        hout = (unsigned short*)hin;
        hin = tmp;
    }

    conv_out_kernel<<<1024, 256, 0, stream>>>(res, conv2W, conv2b, out);
}

// Round 18
// 558.441 us; speedup vs baseline: 1.0544x; 1.0292x over previous
//
#include <hip/hip_runtime.h>
#include <hip/hip_bf16.h>

#define N_ 1024
#define M_ 1152
#define L_ 32
#define NATSTRIDE (L_*M_)   // 36864
#define CONVK 129
#define OUTW 1024
#define NSTEP 31

typedef __attribute__((ext_vector_type(8))) short short8;
typedef __attribute__((ext_vector_type(4))) float f32x4;

__device__ __forceinline__ unsigned short f2bf(float f) {
    unsigned int u = __float_as_uint(f);
    u += 0x7FFFu + ((u >> 16) & 1u);   // round-to-nearest-even
    return (unsigned short)(u >> 16);
}
__device__ __forceinline__ float bf2f(unsigned short b) {
    return __uint_as_float(((unsigned int)b) << 16);
}

// async global->LDS, 16B per lane; lds dest = wave-uniform base + lane*16
__device__ __forceinline__ void gll16(const unsigned short* g, unsigned short* l) {
    __builtin_amdgcn_global_load_lds(
        (const __attribute__((address_space(1))) unsigned int*)g,
        (__attribute__((address_space(3))) unsigned int*)l,
        16, 0, 0);
}

// w0t[m][k] (row-major bf16, for rpre_gemm) and w1blk k-chunk-blocked:
// w1blk[c*9216 + m*8 + e] = bf16(convW[m][8c+e][1])
__global__ __launch_bounds__(256) void build_wsplit(const float* __restrict__ convW,
                                                    unsigned short* __restrict__ w0t,
                                                    unsigned short* __restrict__ w1blk) {
    int idx = blockIdx.x * blockDim.x + threadIdx.x;
    if (idx >= M_ * M_) return;
    int m = idx / M_;
    int k = idx - m * M_;
    const float* s = convW + (size_t)m * (2 * M_) + 2 * k;
    w0t[idx] = f2bf(s[0]);
    int c = k >> 3, e = k & 7;
    w1blk[(size_t)c * 9216 + (size_t)m * 8 + e] = f2bf(s[1]);
}

// h0 (k-chunk-blocked): hblk[c*8192 + n*8 + e] = bf16(NATree[n][L-1][8c+e])
__global__ __launch_bounds__(256) void build_h0(const float* __restrict__ nat,
                                                unsigned short* __restrict__ hblk) {
    int idx = blockIdx.x * blockDim.x + threadIdx.x;   // one thread per 8 elems
    if (idx >= N_ * M_ / 8) return;
    int n = idx / (M_ / 8);
    int c = idx - n * (M_ / 8);
    const float* s = nat + (size_t)n * NATSTRIDE + (size_t)(L_ - 1) * M_ + c * 8;
    f32x4 v0 = *(const f32x4*)(s);
    f32x4 v1 = *(const f32x4*)(s + 4);
    short8 tt;
    #pragma unroll
    for (int e = 0; e < 4; ++e) {
        tt[e]     = (short)f2bf(v0[e]);
        tt[4 + e] = (short)f2bf(v1[e]);
    }
    *(short8*)(hblk + (size_t)c * 8192 + (size_t)n * 8) = tt;
}

// rbf[t][n][m] = bf16(NATree[n][30-t][m])  (row-major)
__global__ __launch_bounds__(256) void build_rbf(const float* __restrict__ nat,
                                                 unsigned short* __restrict__ rbf) {
    int idx = blockIdx.x * blockDim.x + threadIdx.x;   // one thread per 8 elems
    if (idx >= NSTEP * N_ * M_ / 8) return;
    int o = idx * 8;
    int t = o / (N_ * M_);
    int rem = o - t * (N_ * M_);
    int n = rem / M_;
    int m = rem - n * M_;
    int l = (NSTEP - 1) - t;
    const float* s = nat + (size_t)n * NATSTRIDE + (size_t)l * M_ + m;
    f32x4 v0 = *(const f32x4*)(s);
    f32x4 v1 = *(const f32x4*)(s + 4);
    short8 tt;
    #pragma unroll
    for (int e = 0; e < 4; ++e) {
        tt[e]     = (short)f2bf(v0[e]);
        tt[4 + e] = (short)f2bf(v1[e]);
    }
    *(short8*)(rbf + o) = tt;
}

// ---------------- Phase 1: Rpre = bf16( r_t @ W0^T + b ), m97 structure (R17) ----------------
#define P_BM 128
#define P_BN 128
#define P_BK 64
#define P_NT (M_ / P_BK)    // 18

__global__ __launch_bounds__(256) void rpre_gemm(
    const unsigned short* __restrict__ rbf,
    const unsigned short* __restrict__ w0t,
    const float* __restrict__ convb,
    unsigned short* __restrict__ rpre)
{
    __shared__ __align__(16) unsigned short As[P_BM * P_BK];   // 16 KB, linear [row][64]
    __shared__ __align__(16) unsigned short Bs[P_BN * P_BK];   // 16 KB

    int tid = threadIdx.x;
    int lane = tid & 63;
    int w = tid >> 6;
    int wr = w >> 1, wc = w & 1;
    int raw = blockIdx.y * 9 + blockIdx.x;
    int logical = (raw & 7) * 279 + (raw >> 3);   // 2232 = 8*279 bijective chunked swizzle
    int bx = logical % 9, by = logical / 9;
    int n0 = by * P_BM;
    int m0 = bx * P_BN;

    int lr = lane & 15;
    int lk = (lane >> 4) * 8;
    int wbase = tid & ~63;            // wave-uniform chunk base (w*64)

    f32x4 acc[4][4] = {};

    for (int it = 0; it < P_NT; ++it) {
        int kb = it * P_BK;
        if (it) __syncthreads();      // prev compute done before overwrite
        #pragma unroll
        for (int i = 0; i < 4; ++i) {
            int c = i * 256 + tid;    // chunk: row = c>>3, kcol = (c&7)*8
            int row = c >> 3;
            int kc = (c & 7) * 8;
            int lb = (i * 256 + wbase) * 8;   // wave-uniform LDS elem base
            gll16(rbf + (size_t)(n0 + row) * M_ + kb + kc, &As[lb]);
            gll16(w0t + (size_t)(m0 + row) * M_ + kb + kc, &Bs[lb]);
        }
        __syncthreads();              // implicit vmcnt(0) drain -> tiles ready

        #pragma unroll
        for (int ks = 0; ks < P_BK; ks += 32) {
            short8 af[4], bf_[4];
            #pragma unroll
            for (int mi = 0; mi < 4; ++mi)
                af[mi] = *(const short8*)&As[(wr * 64 + mi * 16 + lr) * P_BK + ks + lk];
            #pragma unroll
            for (int ni = 0; ni < 4; ++ni)
                bf_[ni] = *(const short8*)&Bs[(wc * 64 + ni * 16 + lr) * P_BK + ks + lk];
            #pragma unroll
            for (int mi = 0; mi < 4; ++mi)
                #pragma unroll
                for (int ni = 0; ni < 4; ++ni)
                    acc[mi][ni] = __builtin_amdgcn_mfma_f32_16x16x32_bf16(
                        af[mi], bf_[ni], acc[mi][ni], 0, 0, 0);
        }
    }

    #pragma unroll
    for (int mi = 0; mi < 4; ++mi) {
        #pragma unroll
        for (int ni = 0; ni < 4; ++ni) {
            int mloc = m0 + wc * 64 + ni * 16 + lr;
            float bias = convb[mloc];
            #pragma unroll
            for (int j = 0; j < 4; ++j) {
                int g = n0 + wr * 64 + mi * 16 + (lane >> 4) * 4 + j;
                rpre[(size_t)g * M_ + mloc] = f2bf(acc[mi][ni][j] + bias);
            }
        }
    }
}

// ---------------- Phase 3 (x31 launches): nolds_step, 16-row waves ----------------
// 576 blocks = 16 rg (64 rows; bid&15=rg, 16%8==0 -> XCD=rg%8 affinity) x 36 cg
// (32 cols). 4 waves of 16x32 (acc[1][2]) -> 2304 waves = 2.25 waves/SIMD (vs 1.125
// at 288x32x32): TLP finally hides L2 latency. NO LDS, NO barriers; A (hblk) and
// B (w1blk) k-chunk-blocked -> 256B-coalesced fragment loads; depth-4 reg queues.
__global__ __launch_bounds__(256) void nolds_step(
    const unsigned short* __restrict__ hin,     // blocked h
    const unsigned short* __restrict__ w1blk,   // blocked W1
    const unsigned short* __restrict__ rpre_t,
    const unsigned short* __restrict__ rbf_t,
    const float* __restrict__ x,
    unsigned short* __restrict__ hout,          // blocked h
    float* __restrict__ resOut,
    int final_step)
{
    int tid = threadIdx.x;
    int lane = tid & 63;
    int w = tid >> 6;                 // wave -> rows [16w, 16w+16)
    int bid = blockIdx.x;
    int rg = bid & 15;
    int cg = bid >> 4;                // 0..35
    int n0 = rg * 64;
    int m0 = cg * 32;
    int lr = lane & 15;
    int lg = lane >> 4;

    // A: row R0 (one 16-row frag); B: cols m0+lr, m0+16+lr — chunk-blocked, coalesced
    int R0 = n0 + 16 * w + lr;
    const unsigned short* hb0 = hin + (size_t)R0 * 8;
    const unsigned short* wb0 = w1blk + (size_t)(m0 + lr) * 8;
    const unsigned short* wb1 = wb0 + 16 * 8;

    short8 aQ[4], bQ[4][2];
    auto loadQ = [&](int it) {
        int s = it & 3;
        size_t ca = (size_t)(it * 4 + lg) * 8192;
        size_t cb = (size_t)(it * 4 + lg) * 9216;
        aQ[s]    = *(const short8*)(hb0 + ca);
        bQ[s][0] = *(const short8*)(wb0 + cb);
        bQ[s][1] = *(const short8*)(wb1 + cb);
    };
    loadQ(0); loadQ(1); loadQ(2); loadQ(3);

    // epilogue operand prefetch (latency hides under the K-loop)
    unsigned short preR[2][4], rbfR[2][4];
    #pragma unroll
    for (int ni = 0; ni < 2; ++ni) {
        int mloc = m0 + ni * 16 + lr;
        #pragma unroll
        for (int j = 0; j < 4; ++j) {
            int nloc = n0 + 16 * w + lg * 4 + j;
            preR[ni][j] = rpre_t[(size_t)nloc * M_ + mloc];
            rbfR[ni][j] = rbf_t[(size_t)nloc * M_ + mloc];
        }
    }

    // barrier-free K-loop: 36 iters, fully unrolled, 2 MFMA/iter
    f32x4 acc[2] = {};
    #pragma unroll
    for (int it = 0; it < 36; ++it) {
        int s = it & 3;   // compile-time (loop unrolled)
        acc[0] = __builtin_amdgcn_mfma_f32_16x16x32_bf16(aQ[s], bQ[s][0], acc[0], 0, 0, 0);
        acc[1] = __builtin_amdgcn_mfma_f32_16x16x32_bf16(aQ[s], bQ[s][1], acc[1], 0, 0, 0);
        if (it + 4 < 36) loadQ(it + 4);
    }

    // epilogue (plain stores; dispatch boundary provides coherence)
    #pragma unroll
    for (int ni = 0; ni < 2; ++ni) {
        int mloc = m0 + ni * 16 + lr;
        int cB = mloc >> 3, eB = mloc & 7;
        #pragma unroll
        for (int j = 0; j < 4; ++j) {
            int nloc = n0 + 16 * w + lg * 4 + j;
            float pre = acc[ni][j] + bf2f(preR[ni][j]);
            float hv = tanhf(pre) + bf2f(rbfR[ni][j]);
            if (final_step) {
                resOut[(size_t)nloc * M_ + mloc] = tanhf(tanhf(hv) + x[(size_t)nloc * M_ + mloc]);
            } else {
                hout[(size_t)cB * 8192 + (size_t)nloc * 8 + eB] = f2bf(hv);
            }
        }
    }
}

// out[n][j] = conv2b + sum_k res[n][j+k] * conv2W[k]
__global__ __launch_bounds__(256) void conv_out_kernel(
    const float* __restrict__ res, const float* __restrict__ w2,
    const float* __restrict__ b2, float* __restrict__ out)
{
    __shared__ float row[M_];
    __shared__ float wk[CONVK];
    int n = blockIdx.x;
    int tid = threadIdx.x;
    for (int i = tid; i < M_; i += 256) row[i] = res[(size_t)n * M_ + i];
    if (tid < CONVK) wk[tid] = w2[tid];
    __syncthreads();
    float b = b2[0];
    int j0 = tid * 4;
    float s0 = b, s1 = b, s2 = b, s3 = b;
    float r0 = row[j0], r1 = row[j0 + 1], r2 = row[j0 + 2], r3 = row[j0 + 3];
    for (int k = 0; k < CONVK; ++k) {
        float wv = wk[k];
        s0 += r0 * wv; s1 += r1 * wv; s2 += r2 * wv; s3 += r3 * wv;
        if (k < CONVK - 1) { r0 = r1; r1 = r2; r2 = r3; r3 = row[j0 + 4 + k]; }
    }
    float* o = out + (size_t)n * OUTW + j0;
    o[0] = s0; o[1] = s1; o[2] = s2; o[3] = s3;
}

extern "C" void kernel_launch(void* const* d_in, const int* in_sizes, int n_in,
                              void* d_out, int out_size, void* d_ws, size_t ws_size,
                              hipStream_t stream) {
    const float* NATree = (const float*)d_in[0];
    const float* x      = (const float*)d_in[1];
    const float* convW  = (const float*)d_in[2];
    const float* convb  = (const float*)d_in[3];
    const float* conv2W = (const float*)d_in[4];
    const float* conv2b = (const float*)d_in[5];
    float* out = (float*)d_out;

    char* ws = (char*)d_ws;
    size_t off = 0;
    auto alloc = [&](size_t bytes) {
        void* p = ws + off;
        off = (off + bytes + 255) & ~(size_t)255;
        return p;
    };
    unsigned short* w0t   = (unsigned short*)alloc((size_t)M_ * M_ * 2);
    unsigned short* w1blk = (unsigned short*)alloc((size_t)M_ * M_ * 2);
    unsigned short* hA    = (unsigned short*)alloc((size_t)N_ * M_ * 2);
    unsigned short* hB    = (unsigned short*)alloc((size_t)N_ * M_ * 2);
    unsigned short* rpre  = (unsigned short*)alloc((size_t)NSTEP * N_ * M_ * 2);
    unsigned short* rbf   = (unsigned short*)alloc((size_t)NSTEP * N_ * M_ * 2);
    float*          res   = (float*)alloc((size_t)N_ * M_ * 4);

    build_wsplit<<<(M_ * M_ + 255) / 256, 256, 0, stream>>>(convW, w0t, w1blk);
    build_h0<<<(N_ * M_ / 8 + 255) / 256, 256, 0, stream>>>(NATree, hA);
    build_rbf<<<(NSTEP * N_ * M_ / 8 + 255) / 256, 256, 0, stream>>>(NATree, rbf);

    // Phase 1: all 31 r_t @ W0^T + b in one GEMM (M = 31744), gll-staged
    rpre_gemm<<<dim3(M_ / P_BN, (NSTEP * N_) / P_BM), 256, 0, stream>>>(rbf, w0t, convb, rpre);

    // Phase 3: sequential h-chain, no-LDS 16-row-wave step (576 blocks)
    const unsigned short* hin = hA;
    unsigned short* hout = hB;
    for (int t = 0; t < NSTEP; ++t) {
        int fin = (t == NSTEP - 1) ? 1 : 0;
        nolds_step<<<576, 256, 0, stream>>>(
            hin, w1blk, rpre + (size_t)t * N_ * M_, rbf + (size_t)t * N_ * M_,
            x, hout, res, fin);
        unsigned short* tmp = hout;
        hout = (unsigned short*)hin;
        hin = tmp;
    }

    conv_out_kernel<<<1024, 256, 0, stream>>>(res, conv2W, conv2b, out);
}